// Round 1
// baseline (639.143 us; speedup 1.0000x reference)
//
#include <hip/hip_runtime.h>
#include <math.h>

// PrototypicalLoss: B=8192, N=64, D=256 fp32.
// One wave (64 lanes) per batch element. Lane l owns floats [4l, 4l+4) of D.
// Bandwidth trick: only support rows with label==1 are read (~50% of 512 MiB),
// each as a fully-coalesced 1 KiB row.
// THIS ROUND: 8-way batched set-bit extraction so each wave keeps 8 independent
// global_load_dwordx4 in flight (was 1 -> latency-bound at ~0.4 TB/s).

__global__ __launch_bounds__(256) void proto_dist_kernel(
    const float* __restrict__ query,    // (B, 256)
    const float* __restrict__ support,  // (B, 64, 256)
    const int*   __restrict__ labels,   // (B, 64)
    float* __restrict__ dists,          // (B,)
    int B)
{
    const int lane = threadIdx.x & 63;
    const int wv   = threadIdx.x >> 6;
    const int b    = blockIdx.x * 4 + wv;
    if (b >= B) return;

    // Load query early so it overlaps the support streaming.
    const float4 q = ((const float4*)(query + (size_t)b * 256))[lane];

    // one label per lane -> wave-uniform 64-bit mask (SGPR pair)
    const int lab = labels[(size_t)b * 64 + lane];
    const unsigned long long m = __ballot(lab == 1);
    const int count = __popcll(m);

    // support rows for this b, viewed as 64 float4 per row
    const float4* srow = (const float4*)(support + (size_t)b * 64 * 256);

    float4 acc = make_float4(0.f, 0.f, 0.f, 0.f);
    unsigned long long mm = m;
    while (mm) {                        // wave-uniform loop
        // --- extract up to 8 set-bit row indices, branch-free scalar ops ---
        int   n[8];
        float w[8];
        n[0] = __builtin_ctzll(mm);     // while-cond guarantees a bit
        w[0] = 1.0f;
        mm &= (mm - 1ULL);
        #pragma unroll
        for (int j = 1; j < 8; ++j) {
            const bool has = (mm != 0ULL);
            n[j] = has ? __builtin_ctzll(mm) : n[0];  // pad with dup of n[0] (L1 hit)
            w[j] = has ? 1.0f : 0.0f;
            mm   = has ? (mm & (mm - 1ULL)) : 0ULL;
        }
        // --- issue all 8 independent loads before any use ---
        float4 v[8];
        #pragma unroll
        for (int j = 0; j < 8; ++j)
            v[j] = srow[(size_t)n[j] * 64 + lane];
        // --- weighted accumulate (w=0 kills the pad duplicates) ---
        #pragma unroll
        for (int j = 0; j < 8; ++j) {
            acc.x = fmaf(w[j], v[j].x, acc.x);
            acc.y = fmaf(w[j], v[j].y, acc.y);
            acc.z = fmaf(w[j], v[j].z, acc.z);
            acc.w = fmaf(w[j], v[j].w, acc.w);
        }
    }

    float4 proto;
    if (count > 0) {                    // wave-uniform branch
        const float inv = 1.0f / (float)count;
        proto = make_float4(acc.x * inv, acc.y * inv, acc.z * inv, acc.w * inv);
    } else {
        proto = srow[lane];             // fallback: support[b, 0, :]
    }

    const float dx = q.x - proto.x;
    const float dy = q.y - proto.y;
    const float dz = q.z - proto.z;
    const float dw = q.w - proto.w;
    float ss = dx * dx + dy * dy + dz * dz + dw * dw;

    // reduce across the 64-lane wave
    #pragma unroll
    for (int off = 32; off > 0; off >>= 1)
        ss += __shfl_down(ss, off, 64);

    if (lane == 0)
        dists[b] = sqrtf(ss + 1e-8f);
}

__global__ __launch_bounds__(256) void reduce_mean_kernel(
    const float* __restrict__ dists, float* __restrict__ out, int B)
{
    __shared__ float sm[4];
    float s = 0.f;
    for (int i = threadIdx.x; i < B; i += 256)
        s += dists[i];
    #pragma unroll
    for (int off = 32; off > 0; off >>= 1)
        s += __shfl_down(s, off, 64);
    const int lane = threadIdx.x & 63;
    const int wv   = threadIdx.x >> 6;
    if (lane == 0) sm[wv] = s;
    __syncthreads();
    if (threadIdx.x == 0)
        out[0] = (sm[0] + sm[1] + sm[2] + sm[3]) / (float)B;
}

extern "C" void kernel_launch(void* const* d_in, const int* in_sizes, int n_in,
                              void* d_out, int out_size, void* d_ws, size_t ws_size,
                              hipStream_t stream) {
    const float* query   = (const float*)d_in[0];   // (B, D) fp32
    const float* support = (const float*)d_in[1];   // (B, N, D) fp32
    const int*   labels  = (const int*)d_in[2];     // (B, N) int32
    float* out = (float*)d_out;

    const int n_q = in_sizes[0];
    const int n_s = in_sizes[1];
    const int n_l = in_sizes[2];
    const int D = n_s / n_l;        // 256
    const int B = n_q / D;          // 8192
    (void)n_in; (void)out_size; (void)ws_size;

    float* dists = (float*)d_ws;    // B floats of scratch

    const int blocks = (B + 3) / 4; // 4 waves (batch elems) per 256-thread block
    proto_dist_kernel<<<blocks, 256, 0, stream>>>(query, support, labels, dists, B);
    reduce_mean_kernel<<<1, 256, 0, stream>>>(dists, out, B);
}